// Round 13
// baseline (2928.263 us; speedup 1.0000x reference)
//
#include <hip/hip_runtime.h>
#include <stdint.h>

#define SEQ   2048
#define BATCH 128
#define DIN   256
#define DH    512
#define DOUT  256

typedef uint16_t u16;
typedef uint32_t u32;
typedef __attribute__((ext_vector_type(8))) short short8;
typedef __attribute__((ext_vector_type(4))) float f32x4;
typedef __attribute__((ext_vector_type(4))) int i32x4;

#define TWO_LOG2E 2.8853900817779268f   /* 2*log2(e): folded into xp & sc2 */

__device__ __forceinline__ u16 f2bf(float f) {
    u32 u = __float_as_uint(f);
    u += 0x7fffu + ((u >> 16) & 1u);   // RNE
    return (u16)(u >> 16);
}
__device__ __forceinline__ float bf2f(u16 h) {
    return __uint_as_float(((u32)h) << 16);
}

// ---------------------------------------------------------------------------
// Pass A: max|W_hh| (for the int8 scale). 256 blocks x 256 thr x 4 elems.
// ---------------------------------------------------------------------------
__global__ __launch_bounds__(256) void wmax_kernel(const float* __restrict__ W,
                                                   unsigned* __restrict__ wmax) {
    __shared__ float red[256];
    int idx = blockIdx.x * 256 + threadIdx.x;
    float m = 0.f;
#pragma unroll
    for (int j = 0; j < 4; ++j) m = fmaxf(m, fabsf(W[(size_t)idx * 4 + j]));
    red[threadIdx.x] = m;
    __syncthreads();
    for (int s = 128; s > 0; s >>= 1) {
        if (threadIdx.x < s) red[threadIdx.x] = fmaxf(red[threadIdx.x], red[threadIdx.x + s]);
        __syncthreads();
    }
    if (threadIdx.x == 0) atomicMax(wmax, __float_as_uint(red[0]));  // floats >=0: uint order
}

// ---------------------------------------------------------------------------
// Pass B: pack W_hh into int8 MFMA-A-operand fragments, per 16-col slice.
// Wq[(s*8+kc)*1024 + lane*16 + j] =
//     rint( W[s*16+(lane&15)][kc*64+(lane>>4)*16+j] * 127/wmax )
// s = col slice 0..31, kc = 0..7.
// ---------------------------------------------------------------------------
__global__ __launch_bounds__(256) void pack_whh_i8_kernel(
    const float* __restrict__ W, const unsigned* __restrict__ wmax,
    char* __restrict__ Wq) {
    int idx  = blockIdx.x * 256 + threadIdx.x;     // 0..16383
    int lane = idx & 63;
    int kc   = (idx >> 6) & 7;
    int s    = idx >> 9;                            // 0..31
    float sc = 127.0f / __uint_as_float(*wmax);
    int col = s * 16 + (lane & 15);
    int k0  = kc * 64 + (lane >> 4) * 16;
    char q[16];
#pragma unroll
    for (int j = 0; j < 16; ++j)
        q[j] = (char)(int)rintf(W[(size_t)col * DH + k0 + j] * sc);
    *reinterpret_cast<i32x4*>(Wq + (size_t)idx * 16) = *reinterpret_cast<i32x4*>(q);
}

// ---------------------------------------------------------------------------
// Phase 1: xp = 2*log2e*(x @ W_ih^T + b_ih + b_hh), bf16 (pre-scaled so the
// rec epilogue is a raw exp2). SWAPPED-OPERAND MFMA: lane holds 4
// consecutive cols of one batch row -> coalesced uint2 stores.
// ---------------------------------------------------------------------------
__global__ __launch_bounds__(512) void xproj_kernel(
    const float* __restrict__ x, const float* __restrict__ W_ih,
    const float* __restrict__ b_ih, const float* __restrict__ b_hh,
    u16* __restrict__ xp) {
    __shared__ u16 As[128 * 64];
    __shared__ u16 Bs[256 * 64];
    const int tid  = threadIdx.x;
    const int lane = tid & 63;
    const int wid  = tid >> 6;     // 0..7
    const int wm   = wid >> 2;     // 0..1
    const int wn   = wid & 3;      // 0..3
    const int mt   = blockIdx.x;   // 0..2047
    const int nt   = blockIdx.y;   // 0..1

    f32x4 acc[4][4];
#pragma unroll
    for (int i = 0; i < 4; ++i)
#pragma unroll
        for (int j = 0; j < 4; ++j) acc[i][j] = (f32x4){0.f, 0.f, 0.f, 0.f};

    for (int kk = 0; kk < DIN; kk += 64) {
        __syncthreads();
        {   // stage A: 128 rows x 64 k (fp32 -> bf16), 16 elems/thread
            int r = tid >> 2, q = tid & 3;
            const float4* gp = (const float4*)(x + (size_t)(mt * 128 + r) * DIN + kk + q * 16);
            float4 v0 = gp[0], v1 = gp[1], v2 = gp[2], v3 = gp[3];
            short8 h0, h1;
            h0[0]=(short)f2bf(v0.x); h0[1]=(short)f2bf(v0.y); h0[2]=(short)f2bf(v0.z); h0[3]=(short)f2bf(v0.w);
            h0[4]=(short)f2bf(v1.x); h0[5]=(short)f2bf(v1.y); h0[6]=(short)f2bf(v1.z); h0[7]=(short)f2bf(v1.w);
            h1[0]=(short)f2bf(v2.x); h1[1]=(short)f2bf(v2.y); h1[2]=(short)f2bf(v2.z); h1[3]=(short)f2bf(v2.w);
            h1[4]=(short)f2bf(v3.x); h1[5]=(short)f2bf(v3.y); h1[6]=(short)f2bf(v3.z); h1[7]=(short)f2bf(v3.w);
            int base = r * 64, sw = (r & 7) << 3, ke = q * 16;
            *(short8*)&As[base + (ke ^ sw)]       = h0;
            *(short8*)&As[base + ((ke + 8) ^ sw)] = h1;
        }
        {   // stage B: 256 rows x 64 k, 32 elems/thread
            int r = tid >> 1, hf = tid & 1;
            const float4* gp = (const float4*)(W_ih + (size_t)(nt * 256 + r) * DIN + kk + hf * 32);
            int base = r * 64, sw = (r & 7) << 3;
#pragma unroll
            for (int cp = 0; cp < 2; ++cp) {
                float4 u0 = gp[cp*4+0], u1 = gp[cp*4+1], u2 = gp[cp*4+2], u3 = gp[cp*4+3];
                short8 t0, t1;
                t0[0]=(short)f2bf(u0.x); t0[1]=(short)f2bf(u0.y); t0[2]=(short)f2bf(u0.z); t0[3]=(short)f2bf(u0.w);
                t0[4]=(short)f2bf(u1.x); t0[5]=(short)f2bf(u1.y); t0[6]=(short)f2bf(u1.z); t0[7]=(short)f2bf(u1.w);
                t1[0]=(short)f2bf(u2.x); t1[1]=(short)f2bf(u2.y); t1[2]=(short)f2bf(u2.z); t1[3]=(short)f2bf(u2.w);
                t1[4]=(short)f2bf(u3.x); t1[5]=(short)f2bf(u3.y); t1[6]=(short)f2bf(u3.z); t1[7]=(short)f2bf(u3.w);
                int ke = hf * 32 + cp * 16;
                *(short8*)&Bs[base + (ke ^ sw)]       = t0;
                *(short8*)&Bs[base + ((ke + 8) ^ sw)] = t1;
            }
        }
        __syncthreads();
#pragma unroll
        for (int kt = 0; kt < 2; ++kt) {
            short8 a[4], b[4];
            int ke = kt * 32 + (lane >> 4) * 8;
#pragma unroll
            for (int mi = 0; mi < 4; ++mi) {
                int rr = wm * 64 + mi * 16 + (lane & 15);
                a[mi] = *(const short8*)&As[rr * 64 + (ke ^ ((rr & 7) << 3))];
            }
#pragma unroll
            for (int ni = 0; ni < 4; ++ni) {
                int rr = wn * 64 + ni * 16 + (lane & 15);
                b[ni] = *(const short8*)&Bs[rr * 64 + (ke ^ ((rr & 7) << 3))];
            }
            // SWAPPED: A-operand = W_ih frag, B-operand = x frag.
#pragma unroll
            for (int mi = 0; mi < 4; ++mi)
#pragma unroll
                for (int ni = 0; ni < 4; ++ni)
                    acc[mi][ni] = __builtin_amdgcn_mfma_f32_16x16x32_bf16(b[ni], a[mi], acc[mi][ni], 0, 0, 0);
        }
    }
    // epilogue: D row = W col = ni*16 + (lane>>4)*4 + r; D col = batch = lane&15.
    const int lq = lane >> 4;
#pragma unroll
    for (int ni = 0; ni < 4; ++ni) {
        int col0 = nt * 256 + wn * 64 + ni * 16 + lq * 4;
        float4 bi = *(const float4*)(b_ih + col0);
        float4 bh = *(const float4*)(b_hh + col0);
        float bb0 = bi.x + bh.x, bb1 = bi.y + bh.y, bb2 = bi.z + bh.z, bb3 = bi.w + bh.w;
#pragma unroll
        for (int mi = 0; mi < 4; ++mi) {
            float v0 = (acc[mi][ni][0] + bb0) * TWO_LOG2E;
            float v1 = (acc[mi][ni][1] + bb1) * TWO_LOG2E;
            float v2 = (acc[mi][ni][2] + bb2) * TWO_LOG2E;
            float v3 = (acc[mi][ni][3] + bb3) * TWO_LOG2E;
            uint2 v;
            v.x = (u32)f2bf(v0) | ((u32)f2bf(v1) << 16);
            v.y = (u32)f2bf(v2) | ((u32)f2bf(v3) << 16);
            int bbk = wm * 4 + mi;
            int cidx = (nt * 4 + wn) * 4 + ni;
            *(uint2*)(xp + ((((size_t)mt * 8 + bbk) * 32 + cidx) * 64 + lane) * 4) = v;
        }
    }
}

// ---------------------------------------------------------------------------
// Phase 2: recurrence, int8. 8 blocks x 1024 thr (16 waves, 4/SIMD).
// r12 post-mortem: at 8 waves (2/SIMD) the MFMA/VALU/DS pipes serialized —
// step 2995 cyc vs ~1100 ideal overlap. 16 waves give the scheduler 4
// phase-staggered waves per SIMD. Wave owns 32 H-cols -> W = 16 frags =
// 64 pinned regs ("+v" redefinition, r11-proven); demand ~105 fits the
// compiler's 128-reg bin NATURALLY — no fighting. LDS padded to 96 KB to
// pin 1 block/CU (2 blocks would halve the budget and resurrect remat).
// Epilogue: xp pre-scaled by 2*log2e -> raw exp2f (v_exp_f32 IS exp2);
// tanh = 1 - 2*rcp(2^t+1); magic-fma RNE int8; v_perm pack; b32 LDS write.
// ---------------------------------------------------------------------------
__global__ __launch_bounds__(1024) void rnn_rec_kernel(
    const u16* __restrict__ xp, const char* __restrict__ Wq,
    const unsigned* __restrict__ wmax_p, u16* __restrict__ h_last) {
    __shared__ char h_s[2][16 * 512];     // 16 KB : int8 h double buffer
    __shared__ char occ_pad[81920];       // 80 KB occupancy limiter -> 1 blk/CU
    const int tid = threadIdx.x, lane = tid & 63, wv = tid >> 6;  // wv 0..15
    const int bg = blockIdx.x;
    const int row = lane & 15, lq = lane >> 4;
    const int sw = (row & 7) << 4;
    const float sc2 = __uint_as_float(*wmax_p) * (TWO_LOG2E / (127.f * 127.f));

    if (blockIdx.x >= 1000) occ_pad[tid] = 0;   // never true; keeps pad alive

    // W slice (32 cols = 2 n x 8 kc = 16 frags = 64 regs) -> PINNED registers.
    i32x4 wrr[8][2];
#pragma unroll
    for (int kc = 0; kc < 8; ++kc)
#pragma unroll
        for (int n = 0; n < 2; ++n) {
            wrr[kc][n] = *(const i32x4*)(Wq + (size_t)((wv * 2 + n) * 8 + kc) * 1024 + lane * 16);
            asm volatile("" : "+v"(wrr[kc][n]));
        }

    // h(0) = 0 (16 KB via 16 B/thread)
    *(i32x4*)&h_s[0][tid * 16] = (i32x4){0, 0, 0, 0};

    // xp running pointer: cidx = wv*2+n, stride 65536 u16 per step
    const u16* xpp = xp + (((size_t)(bg * 32 + wv * 2) * 64) + lane) * 4;
    uint2 xn[2];
#pragma unroll
    for (int n = 0; n < 2; ++n) xn[n] = *(const uint2*)(xpp + n * 256);
    xpp += 65536;

    __syncthreads();

    for (int t = 0; t < SEQ; ++t) {
        const int cur = t & 1, nxt = cur ^ 1;

        uint2 xc[2];
#pragma unroll
        for (int n = 0; n < 2; ++n) xc[n] = xn[n];
        if (t + 1 < SEQ) {
#pragma unroll
            for (int n = 0; n < 2; ++n) xn[n] = *(const uint2*)(xpp + n * 256);
            xpp += 65536;
        }

        i32x4 acc[2];
        acc[0] = (i32x4){0, 0, 0, 0};
        acc[1] = (i32x4){0, 0, 0, 0};

        // 8 kc chunks: W from pinned regs, h (B-frag) from LDS
#pragma unroll
        for (int kc = 0; kc < 8; ++kc) {
            i32x4 hf = *(const i32x4*)&h_s[cur][row * 512 + ((kc * 64 + lq * 16) ^ sw)];
            acc[0] = __builtin_amdgcn_mfma_i32_16x16x64_i8(wrr[kc][0], hf, acc[0], 0, 0, 0);
            acc[1] = __builtin_amdgcn_mfma_i32_16x16x64_i8(wrr[kc][1], hf, acc[1], 0, 0, 0);
        }

        // epilogue: lane = (batch row = lane&15, cols colb..colb+3)
#pragma unroll
        for (int n = 0; n < 2; ++n) {
            float t0 = fmaf((float)acc[n][0], sc2, __uint_as_float(xc[n].x << 16));
            float t1 = fmaf((float)acc[n][1], sc2, __uint_as_float(xc[n].x & 0xffff0000u));
            float t2 = fmaf((float)acc[n][2], sc2, __uint_as_float(xc[n].y << 16));
            float t3 = fmaf((float)acc[n][3], sc2, __uint_as_float(xc[n].y & 0xffff0000u));
            // t? = 2*log2e*pre ; r = 1/(1+2^t) ; tanh(pre) = 1 - 2r
            float r0 = __builtin_amdgcn_rcpf(exp2f(t0) + 1.0f);
            float r1 = __builtin_amdgcn_rcpf(exp2f(t1) + 1.0f);
            float r2 = __builtin_amdgcn_rcpf(exp2f(t2) + 1.0f);
            float r3 = __builtin_amdgcn_rcpf(exp2f(t3) + 1.0f);
            int colb = wv * 32 + n * 16 + lq * 4;
            if (t == SEQ - 1) {
                float h0 = fmaf(-2.f, r0, 1.f), h1 = fmaf(-2.f, r1, 1.f);
                float h2 = fmaf(-2.f, r2, 1.f), h3 = fmaf(-2.f, r3, 1.f);
                uint2 hv;
                hv.x = (u32)f2bf(h0) | ((u32)f2bf(h1) << 16);
                hv.y = (u32)f2bf(h2) | ((u32)f2bf(h3) << 16);
                *(uint2*)(h_last + (size_t)(bg * 16 + row) * DH + colb) = hv;
            } else {
                // magic-constant RNE: fma(-254, r, 127 + 1.5*2^23) -> int8 in low byte
                u32 b0 = __float_as_uint(fmaf(-254.f, r0, 12583039.f));
                u32 b1 = __float_as_uint(fmaf(-254.f, r1, 12583039.f));
                u32 b2 = __float_as_uint(fmaf(-254.f, r2, 12583039.f));
                u32 b3 = __float_as_uint(fmaf(-254.f, r3, 12583039.f));
                u32 p01 = __builtin_amdgcn_perm(b1, b0, 0x00000400u);
                u32 p23 = __builtin_amdgcn_perm(b3, b2, 0x00000400u);
                u32 pk  = __builtin_amdgcn_perm(p23, p01, 0x05040100u);
                *(u32*)&h_s[nxt][row * 512 + (colb ^ sw)] = pk;
            }
        }
        if (t == SEQ - 1) break;
        __syncthreads();
    }
}

// ---------------------------------------------------------------------------
// Phase 3: out[b][o] = h_last[b,:]·W_fc[o,:] + b_fc[o]   (fp32 VALU, tiny)
// ---------------------------------------------------------------------------
__global__ __launch_bounds__(256) void fc_kernel(
    const u16* __restrict__ h_last, const float* __restrict__ W_fc,
    const float* __restrict__ b_fc, float* __restrict__ out) {
    __shared__ float hsh[DH];
    int b = blockIdx.x, o = threadIdx.x;
    for (int i = threadIdx.x; i < DH; i += 256) hsh[i] = bf2f(h_last[(size_t)b * DH + i]);
    __syncthreads();
    const float* w = W_fc + (size_t)o * DH;
    float s = 0.f;
#pragma unroll 8
    for (int k = 0; k < DH; ++k) s += hsh[k] * w[k];
    out[(size_t)b * DOUT + o] = s + b_fc[o];
}

extern "C" void kernel_launch(void* const* d_in, const int* in_sizes, int n_in,
                              void* d_out, int out_size, void* d_ws, size_t ws_size,
                              hipStream_t stream) {
    const float* x    = (const float*)d_in[0];
    const float* W_ih = (const float*)d_in[1];
    const float* W_hh = (const float*)d_in[2];
    const float* b_ih = (const float*)d_in[3];
    const float* b_hh = (const float*)d_in[4];
    const float* W_fc = (const float*)d_in[5];
    const float* b_fc = (const float*)d_in[6];
    float* out = (float*)d_out;

    char* base    = (char*)d_ws;
    u16*  xp      = (u16*)base;                                   // 256 MiB
    char* Wq      = base + (size_t)SEQ * BATCH * DH * 2;          // 256 KB int8 frags
    u16*  h_last  = (u16*)(Wq + (size_t)DH * DH);                 // 128 KB
    unsigned* wmx = (unsigned*)((char*)h_last + (size_t)BATCH * DH * 2);

    hipMemsetAsync(wmx, 0, sizeof(unsigned), stream);
    hipLaunchKernelGGL(wmax_kernel, dim3(256), dim3(256), 0, stream, W_hh, wmx);
    hipLaunchKernelGGL(pack_whh_i8_kernel, dim3(64), dim3(256), 0, stream, W_hh, wmx, Wq);
    hipLaunchKernelGGL(xproj_kernel, dim3(2048, 2), dim3(512), 0, stream, x, W_ih, b_ih, b_hh, xp);
    hipLaunchKernelGGL(rnn_rec_kernel, dim3(8), dim3(1024), 0, stream, xp, Wq, wmx, h_last);
    hipLaunchKernelGGL(fc_kernel, dim3(128), dim3(256), 0, stream, h_last, W_fc, b_fc, out);
}